// Round 1
// baseline (3889.257 us; speedup 1.0000x reference)
//
#include <hip/hip_runtime.h>
#include <hip/hip_bf16.h>

typedef __hip_bfloat16 bf16;
typedef __attribute__((ext_vector_type(4))) float f32x4;
typedef __attribute__((ext_vector_type(8))) short s16x8;

#define B_ 16
#define T_ 4096
#define D_ 768
#define S_ 768
#define NS 16
#define NIT 9
#define EPS 1e-8f
#define SCALE 0.036084391824351615f  /* 768^-0.5 */

// ---------------------------------------------------------------------------
// float -> bf16 convert
__global__ void f2bf_kernel(const float* __restrict__ in, bf16* __restrict__ out, int n) {
    int i = blockIdx.x * 256 + threadIdx.x;
    if (i < n) out[i] = __float2bfloat16(in[i]);
}

// ---------------------------------------------------------------------------
// LayerNorm over rows of width 768, fp32 in -> bf16 out. One 256-thread block per row.
__global__ void __launch_bounds__(256) ln768_kernel(
    const float* __restrict__ x, const float* __restrict__ g,
    const float* __restrict__ bta, bf16* __restrict__ out)
{
    int row = blockIdx.x;
    int tid = threadIdx.x;
    const float* xr = x + (size_t)row * 768;
    float v0 = xr[tid], v1 = xr[tid + 256], v2 = xr[tid + 512];
    float s = v0 + v1 + v2;
    int lane = tid & 63, wid = tid >> 6;
    #pragma unroll
    for (int off = 32; off; off >>= 1) s += __shfl_down(s, off);
    __shared__ float red[4];
    __shared__ float sh_mu, sh_rs;
    if (lane == 0) red[wid] = s;
    __syncthreads();
    if (tid == 0) sh_mu = (red[0] + red[1] + red[2] + red[3]) * (1.f / 768.f);
    __syncthreads();
    float mu = sh_mu;
    float d0 = v0 - mu, d1 = v1 - mu, d2 = v2 - mu;
    float q = d0 * d0 + d1 * d1 + d2 * d2;
    #pragma unroll
    for (int off = 32; off; off >>= 1) q += __shfl_down(q, off);
    if (lane == 0) red[wid] = q;
    __syncthreads();
    if (tid == 0) sh_rs = rsqrtf((red[0] + red[1] + red[2] + red[3]) * (1.f / 768.f) + 1e-5f);
    __syncthreads();
    float rs = sh_rs;
    bf16* orow = out + (size_t)row * 768;
    orow[tid]       = __float2bfloat16(d0 * rs * g[tid]       + bta[tid]);
    orow[tid + 256] = __float2bfloat16(d1 * rs * g[tid + 256] + bta[tid + 256]);
    orow[tid + 512] = __float2bfloat16(d2 * rs * g[tid + 512] + bta[tid + 512]);
}

// ---------------------------------------------------------------------------
// Generic NT GEMM: C[m,n] = act(alpha * sum_k A[m,k]*B[n,k] + bias[n] (+Cf_old))
// A: [M,K] bf16 row-major (lda=K), B: [N,K] bf16 row-major (ldb=K).
// One wave per 16x16 output tile; 4 waves/block along N.
__global__ void __launch_bounds__(256) gemm_nt_kernel(
    const bf16* __restrict__ A, const bf16* __restrict__ Bm,
    const float* __restrict__ bias, float* __restrict__ Cf, bf16* __restrict__ Cb,
    int M, int N, int K,
    long long sA, long long sB, long long sC,
    float alpha, int relu, int addC)
{
    int wid  = threadIdx.x >> 6;
    int lane = threadIdx.x & 63;
    int mt = blockIdx.x;
    int nt = blockIdx.y * 4 + wid;
    int b  = blockIdx.z;
    const bf16* Ab = A  + (size_t)b * sA;
    const bf16* Bb = Bm + (size_t)b * sB;
    int row  = lane & 15;
    int koff = (lane >> 4) * 8;
    const bf16* ap = Ab + (size_t)(mt * 16 + row) * K + koff;
    const bf16* bp = Bb + (size_t)(nt * 16 + row) * K + koff;
    f32x4 acc = {0.f, 0.f, 0.f, 0.f};
    for (int k = 0; k < K; k += 32) {
        s16x8 af = *reinterpret_cast<const s16x8*>(ap + k);
        s16x8 bf = *reinterpret_cast<const s16x8*>(bp + k);
        acc = __builtin_amdgcn_mfma_f32_16x16x32_bf16(af, bf, acc, 0, 0, 0);
    }
    int col = lane & 15;
    int cn  = nt * 16 + col;
    float bv = bias ? bias[cn] : 0.f;
    size_t cbase = (size_t)b * sC;
    #pragma unroll
    for (int j = 0; j < 4; ++j) {
        int cm = mt * 16 + (lane >> 4) * 4 + j;
        size_t ci = cbase + (size_t)cm * N + cn;
        float val = acc[j] * alpha + bv;
        if (addC) val += Cf[ci];
        if (relu) val = fmaxf(val, 0.f);
        if (Cf) Cf[ci] = val;
        if (Cb) Cb[ci] = __float2bfloat16(val);
    }
}

// ---------------------------------------------------------------------------
// Transpose v [B,T,S] bf16 -> vT [B,S,T] bf16, 32x32 tiles.
__global__ void __launch_bounds__(256) transpose_kernel(
    const bf16* __restrict__ v, bf16* __restrict__ vt)
{
    __shared__ bf16 tile[32][33];
    int b = blockIdx.z;
    int t0 = blockIdx.x * 32, d0 = blockIdx.y * 32;
    int tx = threadIdx.x & 31, ty = threadIdx.x >> 5;  // 8 rows of 32
    const bf16* vb = v + (size_t)b * T_ * S_;
    bf16* vtb = vt + (size_t)b * S_ * T_;
    #pragma unroll
    for (int r = ty; r < 32; r += 8)
        tile[r][tx] = vb[(size_t)(t0 + r) * S_ + d0 + tx];
    __syncthreads();
    #pragma unroll
    for (int r = ty; r < 32; r += 8)
        vtb[(size_t)(d0 + r) * T_ + t0 + tx] = tile[tx][r];
}

// ---------------------------------------------------------------------------
// slots init: broadcast slots_init [16,768] over batch; fp32 + bf16.
__global__ void init_slots_kernel(const float* __restrict__ si,
                                  float* __restrict__ slots, bf16* __restrict__ slots_bf)
{
    int idx = blockIdx.x * 256 + threadIdx.x;  // 256*768
    float v = si[idx % (NS * S_)];
    slots[idx] = v;
    slots_bf[idx] = __float2bfloat16(v);
}

// ---------------------------------------------------------------------------
// softmax over slots axis: attn_vis[b,i,t] = softmax_i(dots[b,i,t])
__global__ void __launch_bounds__(256) softmax_kernel(
    const float* __restrict__ dots, float* __restrict__ av)
{
    int b = blockIdx.y;
    int t = blockIdx.x * 256 + threadIdx.x;
    const float* p = dots + (size_t)b * NS * T_ + t;
    float v[NS];
    float mx = -1e30f;
    #pragma unroll
    for (int i = 0; i < NS; ++i) { v[i] = p[(size_t)i * T_]; mx = fmaxf(mx, v[i]); }
    float s = 0.f;
    #pragma unroll
    for (int i = 0; i < NS; ++i) { v[i] = expf(v[i] - mx); s += v[i]; }
    float r = 1.f / s;
    float* o = av + (size_t)b * NS * T_ + t;
    #pragma unroll
    for (int i = 0; i < NS; ++i) o[(size_t)i * T_] = v[i] * r;
}

// rowsum[bi] = sum_t attn_vis[bi,t] + T*EPS
__global__ void __launch_bounds__(256) rowsum_kernel(
    const float* __restrict__ av, float* __restrict__ rowsum)
{
    int bi = blockIdx.x;
    const float* p = av + (size_t)bi * T_;
    float s = 0.f;
    for (int t = threadIdx.x; t < T_; t += 256) s += p[t];
    int lane = threadIdx.x & 63, wid = threadIdx.x >> 6;
    #pragma unroll
    for (int off = 32; off; off >>= 1) s += __shfl_down(s, off);
    __shared__ float red[4];
    if (lane == 0) red[wid] = s;
    __syncthreads();
    if (threadIdx.x == 0) rowsum[bi] = red[0] + red[1] + red[2] + red[3] + T_ * EPS;
}

// attn_n[bi,t] = (attn_vis + EPS) / rowsum[bi]  (bf16)
__global__ void __launch_bounds__(256) attn_norm_kernel(
    const float* __restrict__ av, const float* __restrict__ rowsum, bf16* __restrict__ an)
{
    size_t idx = (size_t)blockIdx.x * 256 + threadIdx.x;
    int bi = (int)(idx / T_);
    an[idx] = __float2bfloat16((av[idx] + EPS) / rowsum[bi]);
}

// ---------------------------------------------------------------------------
// GRU gates: slots <- GRUCell(updates, slots)
__global__ void __launch_bounds__(256) gru_gates_kernel(
    const float* __restrict__ gi, const float* __restrict__ gh,
    float* __restrict__ slots, bf16* __restrict__ slots_bf)
{
    int idx = blockIdx.x * 256 + threadIdx.x;  // 256*768
    int r = idx / 768, c = idx - r * 768;
    const float* gir = gi + (size_t)r * 2304;
    const float* ghr = gh + (size_t)r * 2304;
    float ir = gir[c], iz = gir[768 + c], inn = gir[1536 + c];
    float hr = ghr[c], hz = ghr[768 + c], hn  = ghr[1536 + c];
    float rg = 1.f / (1.f + expf(-(ir + hr)));
    float z  = 1.f / (1.f + expf(-(iz + hz)));
    float n  = tanhf(inn + rg * hn);
    float h  = slots[idx];
    float out = (1.f - z) * n + z * h;
    slots[idx] = out;
    slots_bf[idx] = __float2bfloat16(out);
}

// ---------------------------------------------------------------------------
// Clustering (one block per batch): adjacency + transitive closure + means + mask
__global__ void __launch_bounds__(256) cluster_kernel(
    const float* __restrict__ slots, float* __restrict__ out_slots,
    float* __restrict__ out_mask, float* __restrict__ cm_g)
{
    int b = blockIdx.x;
    __shared__ float s[16][768];
    __shared__ float inv[16];
    __shared__ float adj[16][16], tmp[16][16], cw[16][16];
    __shared__ int reset_s;
    const float* sb = slots + (size_t)b * 16 * 768;
    for (int i = threadIdx.x; i < 16 * 768; i += 256) s[i / 768][i % 768] = sb[i];
    __syncthreads();
    if (threadIdx.x < 16) {
        float q = 0.f;
        for (int d = 0; d < 768; ++d) q += s[threadIdx.x][d] * s[threadIdx.x][d];
        float nr = fmaxf(sqrtf(q), 1e-12f);
        inv[threadIdx.x] = 1.f / nr;
    }
    __syncthreads();
    int n = threadIdx.x >> 4, m = threadIdx.x & 15;
    float dot = 0.f;
    for (int d = 0; d < 768; ++d) dot += s[n][d] * s[m][d];
    dot *= inv[n] * inv[m];
    float dist = 1.f - dot;
    adj[n][m] = (dist < 0.5f) ? 1.f : 0.f;
    __syncthreads();
    #pragma unroll
    for (int it = 0; it < 4; ++it) {
        float t = 0.f;
        #pragma unroll
        for (int j = 0; j < 16; ++j) t += adj[n][j] * adj[j][m];
        tmp[n][m] = fminf(t, 1.f);
        __syncthreads();
        adj[n][m] = tmp[n][m];
        __syncthreads();
    }
    // cumsum down columns; keep rows where inclusive cumsum <= 1
    if (threadIdx.x < 16) {
        int mm = threadIdx.x;
        float run = 0.f;
        for (int nn = 0; nn < 16; ++nn) {
            run += adj[nn][mm];
            tmp[nn][mm] = adj[nn][mm] * ((run <= 1.f) ? 1.f : 0.f);
        }
    }
    __syncthreads();
    if (threadIdx.x == 0) {
        int cnt = 0;
        for (int nn = 0; nn < 16; ++nn) {
            bool any = false;
            for (int j = 0; j < 16; ++j) any = any || (tmp[nn][j] > 0.f);
            cnt += any ? 1 : 0;
        }
        reset_s = (cnt < 3) ? 1 : 0;
    }
    __syncthreads();
    if (reset_s) tmp[n][m] = (n == m) ? 1.f : 0.f;
    __syncthreads();
    if (threadIdx.x < 16) {
        float rs = 0.f;
        for (int j = 0; j < 16; ++j) rs += tmp[threadIdx.x][j];
        rs = fmaxf(rs, 1.f);
        for (int j = 0; j < 16; ++j) cw[threadIdx.x][j] = tmp[threadIdx.x][j] / rs;
        bool any = false;
        for (int j = 0; j < 16; ++j) any = any || (tmp[threadIdx.x][j] > 0.f);
        out_mask[b * 16 + threadIdx.x] = any ? 1.f : 0.f;
    }
    cm_g[b * 256 + threadIdx.x] = tmp[n][m];
    __syncthreads();
    for (int i = threadIdx.x; i < 16 * 768; i += 256) {
        int nn = i / 768, d = i - nn * 768;
        float acc = 0.f;
        #pragma unroll
        for (int j = 0; j < 16; ++j) acc += cw[nn][j] * s[j][d];
        out_slots[(size_t)b * 16 * 768 + i] = acc;
    }
}

// out_attn[b,t,i] = sum_j cm[b,i,j] * attn_vis[b,j,t]
__global__ void __launch_bounds__(256) cattn_kernel(
    const float* __restrict__ av, const float* __restrict__ cm_g, float* __restrict__ out_attn)
{
    int b = blockIdx.y;
    int t = blockIdx.x * 256 + threadIdx.x;
    __shared__ float cm[16][16];
    cm[threadIdx.x >> 4][threadIdx.x & 15] = cm_g[b * 256 + threadIdx.x];
    __syncthreads();
    float avv[16];
    #pragma unroll
    for (int j = 0; j < 16; ++j) avv[j] = av[((size_t)b * 16 + j) * T_ + t];
    #pragma unroll
    for (int i = 0; i < 16; ++i) {
        float acc = 0.f;
        #pragma unroll
        for (int j = 0; j < 16; ++j) acc += cm[i][j] * avv[j];
        out_attn[((size_t)b * T_ + t) * 16 + i] = acc;
    }
}

// ---------------------------------------------------------------------------
static inline void gemm(hipStream_t st, const bf16* A, const bf16* Bm, const float* bias,
                        float* Cf, bf16* Cb, int M, int N, int K,
                        long long sA, long long sB, long long sC, int batch,
                        float alpha, int relu, int addC)
{
    dim3 g(M / 16, N / 64, batch), blk(256);
    gemm_nt_kernel<<<g, blk, 0, st>>>(A, Bm, bias, Cf, Cb, M, N, K, sA, sB, sC, alpha, relu, addC);
}

extern "C" void kernel_launch(void* const* d_in, const int* in_sizes, int n_in,
                              void* d_out, int out_size, void* d_ws, size_t ws_size,
                              hipStream_t stream)
{
    const float* x    = (const float*)d_in[0];
    const float* si   = (const float*)d_in[3];
    const float* Wk   = (const float*)d_in[4];
    const float* Wv   = (const float*)d_in[5];
    const float* Wq   = (const float*)d_in[6];
    const float* gwih = (const float*)d_in[7];
    const float* gwhh = (const float*)d_in[8];
    const float* gbih = (const float*)d_in[9];
    const float* gbhh = (const float*)d_in[10];
    const float* w1   = (const float*)d_in[11];
    const float* b1   = (const float*)d_in[12];
    const float* w2   = (const float*)d_in[13];
    const float* b2   = (const float*)d_in[14];
    const float* ling = (const float*)d_in[15];
    const float* linb = (const float*)d_in[16];
    const float* lsg  = (const float*)d_in[17];
    const float* lsb  = (const float*)d_in[18];
    const float* lfg  = (const float*)d_in[19];
    const float* lfb  = (const float*)d_in[20];

    // workspace carve-up (bytes, 256-aligned)
    char* w = (char*)d_ws;
    size_t off = 0;
    auto alloc = [&](size_t bytes) { void* p = w + off; off += (bytes + 255) & ~(size_t)255; return p; };
    bf16* xn_vt  = (bf16*)alloc((size_t)B_ * T_ * D_ * 2);   // xn, later vT
    bf16* k_bf   = (bf16*)alloc((size_t)B_ * T_ * S_ * 2);
    bf16* v_bf   = (bf16*)alloc((size_t)B_ * T_ * S_ * 2);
    float* dots  = (float*)alloc((size_t)B_ * NS * T_ * 4);
    float* avis  = (float*)alloc((size_t)B_ * NS * T_ * 4);
    bf16* an     = (bf16*)alloc((size_t)B_ * NS * T_ * 2);
    float* rsum  = (float*)alloc(B_ * NS * 4);
    float* slots = (float*)alloc((size_t)B_ * NS * S_ * 4);
    bf16* slots_bf = (bf16*)alloc((size_t)B_ * NS * S_ * 2);
    bf16* lnsl   = (bf16*)alloc((size_t)B_ * NS * S_ * 2);
    bf16* q_bf   = (bf16*)alloc((size_t)B_ * NS * S_ * 2);
    bf16* upd_bf = (bf16*)alloc((size_t)B_ * NS * S_ * 2);
    float* gi    = (float*)alloc((size_t)B_ * NS * 3 * S_ * 4);
    float* gh    = (float*)alloc((size_t)B_ * NS * 3 * S_ * 4);
    bf16* h1_bf  = (bf16*)alloc((size_t)B_ * NS * 4 * S_ * 2);
    bf16* wq_bf  = (bf16*)alloc((size_t)S_ * S_ * 2);
    bf16* wk_bf  = (bf16*)alloc((size_t)S_ * D_ * 2);
    bf16* wv_bf  = (bf16*)alloc((size_t)S_ * D_ * 2);
    bf16* gwih_bf = (bf16*)alloc((size_t)3 * S_ * S_ * 2);
    bf16* gwhh_bf = (bf16*)alloc((size_t)3 * S_ * S_ * 2);
    bf16* w1_bf  = (bf16*)alloc((size_t)4 * S_ * S_ * 2);
    bf16* w2_bf  = (bf16*)alloc((size_t)S_ * 4 * S_ * 2);
    float* cm_g  = (float*)alloc((size_t)B_ * 256 * 4);

    float* out_slots = (float*)d_out;
    float* out_attn  = out_slots + (size_t)B_ * NS * S_;
    float* out_mask  = out_attn + (size_t)B_ * T_ * NS;

    // --- weight conversions
    auto cvt = [&](const float* src, bf16* dst, int n) {
        f2bf_kernel<<<(n + 255) / 256, 256, 0, stream>>>(src, dst, n);
    };
    cvt(Wq, wq_bf, S_ * S_);
    cvt(Wk, wk_bf, S_ * D_);
    cvt(Wv, wv_bf, S_ * D_);
    cvt(gwih, gwih_bf, 3 * S_ * S_);
    cvt(gwhh, gwhh_bf, 3 * S_ * S_);
    cvt(w1, w1_bf, 4 * S_ * S_);
    cvt(w2, w2_bf, S_ * 4 * S_);

    // --- LN(x) -> xn (bf16)
    ln768_kernel<<<B_ * T_, 256, 0, stream>>>(x, ling, linb, xn_vt);

    // --- k, v projections
    gemm(stream, xn_vt, wk_bf, nullptr, nullptr, k_bf, B_ * T_, S_, D_, 0, 0, 0, 1, 1.f, 0, 0);
    gemm(stream, xn_vt, wv_bf, nullptr, nullptr, v_bf, B_ * T_, S_, D_, 0, 0, 0, 1, 1.f, 0, 0);

    // --- vT (reuse xn buffer)
    {
        dim3 g(T_ / 32, S_ / 32, B_);
        transpose_kernel<<<g, 256, 0, stream>>>(v_bf, xn_vt);
    }
    bf16* vT = xn_vt;

    // --- slots init
    init_slots_kernel<<<(B_ * NS * S_) / 256, 256, 0, stream>>>(si, slots, slots_bf);

    for (int it = 0; it < NIT; ++it) {
        // q = ln(slots) @ Wq.T
        ln768_kernel<<<B_ * NS, 256, 0, stream>>>(slots, lsg, lsb, lnsl);
        gemm(stream, lnsl, wq_bf, nullptr, nullptr, q_bf, B_ * NS, S_, S_, 0, 0, 0, 1, 1.f, 0, 0);
        // dots[b] = q[b] @ k[b]^T * SCALE   (M=16, N=T, K=768)
        gemm(stream, q_bf, k_bf, nullptr, dots, nullptr, NS, T_, S_,
             (long long)NS * S_, (long long)T_ * S_, (long long)NS * T_, B_, SCALE, 0, 0);
        // softmax over slots, then T-normalization
        {
            dim3 g(T_ / 256, B_);
            softmax_kernel<<<g, 256, 0, stream>>>(dots, avis);
        }
        rowsum_kernel<<<B_ * NS, 256, 0, stream>>>(avis, rsum);
        attn_norm_kernel<<<(B_ * NS * T_) / 256, 256, 0, stream>>>(avis, rsum, an);
        // updates[b] = attn_n[b] @ vT[b]^T-ish  (M=16, N=768, K=T)
        gemm(stream, an, vT, nullptr, nullptr, upd_bf, NS, S_, T_,
             (long long)NS * T_, (long long)S_ * T_, (long long)NS * S_, B_, 1.f, 0, 0);
        // GRU
        gemm(stream, upd_bf, gwih_bf, gbih, gi, nullptr, B_ * NS, 3 * S_, S_, 0, 0, 0, 1, 1.f, 0, 0);
        gemm(stream, slots_bf, gwhh_bf, gbhh, gh, nullptr, B_ * NS, 3 * S_, S_, 0, 0, 0, 1, 1.f, 0, 0);
        gru_gates_kernel<<<(B_ * NS * S_) / 256, 256, 0, stream>>>(gi, gh, slots, slots_bf);
        // MLP residual
        ln768_kernel<<<B_ * NS, 256, 0, stream>>>(slots, lfg, lfb, lnsl);
        gemm(stream, lnsl, w1_bf, b1, nullptr, h1_bf, B_ * NS, 4 * S_, S_, 0, 0, 0, 1, 1.f, 1, 0);
        gemm(stream, h1_bf, w2_bf, b2, slots, slots_bf, B_ * NS, S_, 4 * S_, 0, 0, 0, 1, 1.f, 0, 1);
    }

    // --- clustering epilogue
    cluster_kernel<<<B_, 256, 0, stream>>>(slots, out_slots, out_mask, cm_g);
    {
        dim3 g(T_ / 256, B_);
        cattn_kernel<<<g, 256, 0, stream>>>(avis, cm_g, out_attn);
    }
}

// Round 2
// 1669.378 us; speedup vs baseline: 2.3298x; 2.3298x over previous
//
#include <hip/hip_runtime.h>
#include <hip/hip_bf16.h>

typedef __hip_bfloat16 bf16;
typedef __attribute__((ext_vector_type(4))) float f32x4;
typedef __attribute__((ext_vector_type(8))) short s16x8;
typedef unsigned int u32;
typedef unsigned short u16;

#define B_ 16
#define T_ 4096
#define D_ 768
#define S_ 768
#define NS 16
#define NIT 9
#define NCHUNK 16
#define TCH 256
#define EPS 1e-8f
#define SCALE 0.036084391824351615f  /* 768^-0.5 */

__device__ __forceinline__ void gld16(const void* g, void* l) {
    __builtin_amdgcn_global_load_lds((const __attribute__((address_space(1))) u32*)g,
                                     (__attribute__((address_space(3))) u32*)l, 16, 0, 0);
}

__device__ __forceinline__ u16 bfbits(float x) {
    bf16 h = __float2bfloat16(x);
    return *reinterpret_cast<u16*>(&h);
}

// ---------------------------------------------------------------------------
__global__ void f2bf_kernel(const float* __restrict__ in, bf16* __restrict__ out, int n) {
    int i = blockIdx.x * 256 + threadIdx.x;
    if (i < n) out[i] = __float2bfloat16(in[i]);
}

// ---------------------------------------------------------------------------
// LayerNorm over rows of width 768, fp32 in -> bf16 out. One 256-thread block per row.
__global__ void __launch_bounds__(256) ln768_kernel(
    const float* __restrict__ x, const float* __restrict__ g,
    const float* __restrict__ bta, bf16* __restrict__ out)
{
    int row = blockIdx.x;
    int tid = threadIdx.x;
    const float* xr = x + (size_t)row * 768;
    float v0 = xr[tid], v1 = xr[tid + 256], v2 = xr[tid + 512];
    float s = v0 + v1 + v2;
    int lane = tid & 63, wid = tid >> 6;
    #pragma unroll
    for (int off = 32; off; off >>= 1) s += __shfl_down(s, off);
    __shared__ float red[4];
    __shared__ float sh_mu, sh_rs;
    if (lane == 0) red[wid] = s;
    __syncthreads();
    if (tid == 0) sh_mu = (red[0] + red[1] + red[2] + red[3]) * (1.f / 768.f);
    __syncthreads();
    float mu = sh_mu;
    float d0 = v0 - mu, d1 = v1 - mu, d2 = v2 - mu;
    float q = d0 * d0 + d1 * d1 + d2 * d2;
    #pragma unroll
    for (int off = 32; off; off >>= 1) q += __shfl_down(q, off);
    if (lane == 0) red[wid] = q;
    __syncthreads();
    if (tid == 0) sh_rs = rsqrtf((red[0] + red[1] + red[2] + red[3]) * (1.f / 768.f) + 1e-5f);
    __syncthreads();
    float rs = sh_rs;
    bf16* orow = out + (size_t)row * 768;
    orow[tid]       = __float2bfloat16(d0 * rs * g[tid]       + bta[tid]);
    orow[tid + 256] = __float2bfloat16(d1 * rs * g[tid + 256] + bta[tid + 256]);
    orow[tid + 512] = __float2bfloat16(d2 * rs * g[tid + 512] + bta[tid + 512]);
}

// ---------------------------------------------------------------------------
// 128x128 tiled NT GEMM, BK=64, global_load_lds staging, XOR-swizzled LDS.
// C[m,n] = sum_k A[m,k]*B[n,k]; A [M,K], B [N,K] bf16 row-major; C bf16.
__global__ void __launch_bounds__(256) gemm128_kernel(
    const bf16* __restrict__ A, const bf16* __restrict__ Bm, bf16* __restrict__ Cb,
    int M, int N, int K)
{
    __shared__ bf16 As[128 * 64];  // [128 rows][128 bytes], swizzled
    __shared__ bf16 Bs[128 * 64];
    int tid = threadIdx.x, lane = tid & 63, wid = tid >> 6;
    int bm0 = blockIdx.x * 128, bn0 = blockIdx.y * 128;
    int wr = wid >> 1, wc = wid & 1;
    int g = lane >> 4, r15 = lane & 15;
    const f32x4 vzero = {0.f, 0.f, 0.f, 0.f};
    f32x4 acc[4][4];
    #pragma unroll
    for (int m = 0; m < 4; ++m)
        #pragma unroll
        for (int n = 0; n < 4; ++n) acc[m][n] = vzero;

    for (int kt = 0; kt < K; kt += 64) {
        __syncthreads();
        #pragma unroll
        for (int i = 0; i < 4; ++i) {
            int sa = wid * 64 + i * 256;            // uniform per wave
            int o = (sa + lane) * 16;
            int r = o >> 7, cb = o & 127;
            int cbs = cb ^ ((r & 7) << 4);
            gld16(A + (size_t)(bm0 + r) * K + kt + (cbs >> 1), (char*)As + (size_t)sa * 16);
        }
        #pragma unroll
        for (int i = 0; i < 4; ++i) {
            int sa = wid * 64 + i * 256;
            int o = (sa + lane) * 16;
            int r = o >> 7, cb = o & 127;
            int cbs = cb ^ ((r & 7) << 4);
            gld16(Bm + (size_t)(bn0 + r) * K + kt + (cbs >> 1), (char*)Bs + (size_t)sa * 16);
        }
        asm volatile("s_waitcnt vmcnt(0)" ::: "memory");
        __syncthreads();
        #pragma unroll
        for (int kk = 0; kk < 64; kk += 32) {
            s16x8 af[4], bfr[4];
            #pragma unroll
            for (int m = 0; m < 4; ++m) {
                int r = wr * 64 + m * 16 + r15;
                int p = r * 128 + ((kk * 2 + g * 16) ^ ((r & 7) << 4));
                af[m] = *(const s16x8*)((const char*)As + p);
            }
            #pragma unroll
            for (int n = 0; n < 4; ++n) {
                int r = wc * 64 + n * 16 + r15;
                int p = r * 128 + ((kk * 2 + g * 16) ^ ((r & 7) << 4));
                bfr[n] = *(const s16x8*)((const char*)Bs + p);
            }
            #pragma unroll
            for (int m = 0; m < 4; ++m)
                #pragma unroll
                for (int n = 0; n < 4; ++n)
                    acc[m][n] = __builtin_amdgcn_mfma_f32_16x16x32_bf16(af[m], bfr[n], acc[m][n], 0, 0, 0);
        }
    }
    #pragma unroll
    for (int m = 0; m < 4; ++m) {
        int cm = bm0 + wr * 64 + m * 16 + g * 4;
        #pragma unroll
        for (int n = 0; n < 4; ++n) {
            int cn = bn0 + wc * 64 + n * 16 + r15;
            #pragma unroll
            for (int j = 0; j < 4; ++j)
                Cb[(size_t)(cm + j) * N + cn] = __float2bfloat16(acc[m][n][j]);
        }
    }
}

// ---------------------------------------------------------------------------
// Skinny NT GEMM for M multiple of 16: BM=16, BN=64, BK=64, LDS-staged.
// C = act(acc + bias (+Cf_old)); optional f32/bf16 outputs.
__global__ void __launch_bounds__(256) gemm_skinny_kernel(
    const bf16* __restrict__ A, const bf16* __restrict__ Bm,
    const float* __restrict__ bias, float* __restrict__ Cf, bf16* __restrict__ Cb,
    int M, int N, int K, int relu, int addC)
{
    __shared__ bf16 As[16 * 64];   // [16][128B] swizzled  (2KB)
    __shared__ bf16 Bs[64 * 64];   // [64][128B] swizzled  (8KB)
    int tid = threadIdx.x, lane = tid & 63, wid = tid >> 6;
    int bm0 = blockIdx.x * 16, bn0 = blockIdx.y * 64;
    int g = lane >> 4, r15 = lane & 15;
    const f32x4 vzero = {0.f, 0.f, 0.f, 0.f};
    f32x4 acc = vzero;
    for (int kt = 0; kt < K; kt += 64) {
        __syncthreads();
        #pragma unroll
        for (int i = 0; i < 3; ++i) {
            int s0 = i * 256 + wid * 64;   // seg base, uniform per wave
            if (s0 < 640) {
                int o = (s0 + lane) * 16;
                if (o < 2048) {            // A region: segs 0..127
                    int r = o >> 7, cb = o & 127;
                    int cbs = cb ^ ((r & 7) << 4);
                    gld16(A + (size_t)(bm0 + r) * K + kt + (cbs >> 1), (char*)As + (size_t)s0 * 16);
                } else {                   // B region: segs 128..639
                    int ob = o - 2048;
                    int r = ob >> 7, cb = ob & 127;
                    int cbs = cb ^ ((r & 7) << 4);
                    gld16(Bm + (size_t)(bn0 + r) * K + kt + (cbs >> 1),
                          (char*)Bs + (size_t)(s0 * 16 - 2048));
                }
            }
        }
        asm volatile("s_waitcnt vmcnt(0)" ::: "memory");
        __syncthreads();
        #pragma unroll
        for (int kk = 0; kk < 64; kk += 32) {
            int ra = r15;
            int pa = ra * 128 + ((kk * 2 + g * 16) ^ ((ra & 7) << 4));
            s16x8 af = *(const s16x8*)((const char*)As + pa);
            int rb = wid * 16 + r15;
            int pb = rb * 128 + ((kk * 2 + g * 16) ^ ((rb & 7) << 4));
            s16x8 bfr = *(const s16x8*)((const char*)Bs + pb);
            acc = __builtin_amdgcn_mfma_f32_16x16x32_bf16(af, bfr, acc, 0, 0, 0);
        }
    }
    int cn = bn0 + wid * 16 + r15;
    float bv = bias ? bias[cn] : 0.f;
    #pragma unroll
    for (int j = 0; j < 4; ++j) {
        int cm = bm0 + g * 4 + j;
        size_t ci = (size_t)cm * N + cn;
        float val = acc[j] + bv;
        if (addC) val += Cf[ci];
        if (relu) val = fmaxf(val, 0.f);
        if (Cf) Cf[ci] = val;
        if (Cb) Cb[ci] = __float2bfloat16(val);
    }
}

// ---------------------------------------------------------------------------
// Transpose v [B,T,S] bf16 -> vT [B,S,T] bf16, 32x32 tiles.
__global__ void __launch_bounds__(256) transpose_kernel(
    const bf16* __restrict__ v, bf16* __restrict__ vt)
{
    __shared__ bf16 tile[32][33];
    int b = blockIdx.z;
    int t0 = blockIdx.x * 32, d0 = blockIdx.y * 32;
    int tx = threadIdx.x & 31, ty = threadIdx.x >> 5;
    const bf16* vb = v + (size_t)b * T_ * S_;
    bf16* vtb = vt + (size_t)b * S_ * T_;
    #pragma unroll
    for (int r = ty; r < 32; r += 8)
        tile[r][tx] = vb[(size_t)(t0 + r) * S_ + d0 + tx];
    __syncthreads();
    #pragma unroll
    for (int r = ty; r < 32; r += 8)
        vtb[(size_t)(d0 + r) * T_ + t0 + tx] = tile[tx][r];
}

// vsum[row] = sum_t vT[row][t]  (row = b*768+d), one wave per row
__global__ void __launch_bounds__(256) vsum_kernel(
    const bf16* __restrict__ vT, float* __restrict__ vsum)
{
    int row = blockIdx.x * 4 + (threadIdx.x >> 6);
    int lane = threadIdx.x & 63;
    const bf16* p = vT + (size_t)row * T_;
    float s = 0.f;
    for (int t = lane * 8; t < T_; t += 64 * 8) {
        s16x8 v8 = *(const s16x8*)(p + t);
        #pragma unroll
        for (int j = 0; j < 8; ++j) {
            union { u32 i; float f; } c;
            c.i = ((u32)(u16)v8[j]) << 16;
            s += c.f;
        }
    }
    #pragma unroll
    for (int off = 32; off; off >>= 1) s += __shfl_down(s, off);
    if (lane == 0) vsum[row] = s;
}

// ---------------------------------------------------------------------------
// slots init
__global__ void init_slots_kernel(const float* __restrict__ si,
                                  float* __restrict__ slots, bf16* __restrict__ slots_bf)
{
    int idx = blockIdx.x * 256 + threadIdx.x;  // 256*768
    float v = si[idx % (NS * S_)];
    slots[idx] = v;
    slots_bf[idx] = __float2bfloat16(v);
}

// ---------------------------------------------------------------------------
// Fused attention step: per (batch, t-chunk of 256):
//   dotsT = k_tile @ q^T * SCALE ; softmax over slots (local per t);
//   partial U^T[d][s] += vT_tile @ a^T ; partial rowsum[s] += sum_t a.
// Writes pU [b][chunk][d][s] f32, prs [b][chunk][s], optionally avis.
__global__ void __launch_bounds__(256) fused_attn_kernel(
    const bf16* __restrict__ q_bf, const bf16* __restrict__ k_bf, const bf16* __restrict__ vT,
    float* __restrict__ pU, float* __restrict__ prs, float* __restrict__ avis, int write_avis)
{
    __shared__ bf16 qs[16 * 768];    // [16][1536B] swizzled (24KB)
    __shared__ bf16 ks[32 * 768];    // [32][1536B] swizzled (48KB)
    __shared__ bf16 vs[768 * 32];    // [768][64B]  swizzled (48KB)
    __shared__ bf16 as_[16 * 32];    // [16][64B]   swizzled (1KB)
    __shared__ float rsw[2][16];
    int tid = threadIdx.x, lane = tid & 63, wid = tid >> 6;
    int b = blockIdx.x >> 4, chunk = blockIdx.x & 15;
    int t0 = chunk * TCH;
    int g = lane >> 4, s15 = lane & 15;
    const bf16* qb  = q_bf + (size_t)(b * 16) * 768;
    const bf16* kb  = k_bf + (size_t)b * T_ * 768;
    const bf16* vtb = vT   + (size_t)b * 768 * T_;

    // stage q once (1536 segs)
    #pragma unroll
    for (int i = 0; i < 6; ++i) {
        int s0 = i * 256 + wid * 64;
        int o = (s0 + lane) * 16;
        int r = o / 1536, cb = o % 1536;
        int cbs = cb ^ ((r & 7) << 4);
        gld16(qb + (size_t)r * 768 + (cbs >> 1), (char*)qs + (size_t)s0 * 16);
    }

    const f32x4 vzero = {0.f, 0.f, 0.f, 0.f};
    f32x4 uacc[12];
    #pragma unroll
    for (int i = 0; i < 12; ++i) uacc[i] = vzero;
    float rs_acc = 0.f;

    for (int ts = 0; ts < TCH / 32; ++ts) {
        int tb = t0 + ts * 32;
        __syncthreads();   // previous step's LDS reads done
        #pragma unroll
        for (int i = 0; i < 12; ++i) {   // k-tile: [32][1536B]
            int s0 = i * 256 + wid * 64;
            int o = (s0 + lane) * 16;
            int r = o / 1536, cb = o % 1536;
            int cbs = cb ^ ((r & 7) << 4);
            gld16(kb + (size_t)(tb + r) * 768 + (cbs >> 1), (char*)ks + (size_t)s0 * 16);
        }
        #pragma unroll
        for (int i = 0; i < 12; ++i) {   // vT-tile: [768][64B]
            int s0 = i * 256 + wid * 64;
            int o = (s0 + lane) * 16;
            int d = o >> 6, cb = o & 63;
            int cbs = cb ^ ((d & 3) << 4);
            gld16(vtb + (size_t)d * T_ + tb + (cbs >> 1), (char*)vs + (size_t)s0 * 16);
        }
        asm volatile("s_waitcnt vmcnt(0)" ::: "memory");
        __syncthreads();

        if (wid < 2) {
            f32x4 dacc = vzero;
            #pragma unroll
            for (int kk = 0; kk < 768; kk += 32) {
                int rk = wid * 16 + s15;
                int pk = rk * 1536 + ((kk * 2 + g * 16) ^ ((rk & 7) << 4));
                s16x8 kf = *(const s16x8*)((const char*)ks + pk);
                int pq = s15 * 1536 + ((kk * 2 + g * 16) ^ ((s15 & 7) << 4));
                s16x8 qf = *(const s16x8*)((const char*)qs + pq);
                dacc = __builtin_amdgcn_mfma_f32_16x16x32_bf16(kf, qf, dacc, 0, 0, 0);
            }
            float d0 = dacc[0] * SCALE, d1 = dacc[1] * SCALE,
                  d2 = dacc[2] * SCALE, d3 = dacc[3] * SCALE;
            // softmax over slots: reduce across lanes 0-15 of each 16-lane group
            float m0 = d0, m1 = d1, m2 = d2, m3 = d3;
            #pragma unroll
            for (int off = 1; off < 16; off <<= 1) {
                m0 = fmaxf(m0, __shfl_xor(m0, off));
                m1 = fmaxf(m1, __shfl_xor(m1, off));
                m2 = fmaxf(m2, __shfl_xor(m2, off));
                m3 = fmaxf(m3, __shfl_xor(m3, off));
            }
            float e0 = expf(d0 - m0), e1 = expf(d1 - m1), e2 = expf(d2 - m2), e3 = expf(d3 - m3);
            float q0 = e0, q1 = e1, q2 = e2, q3 = e3;
            #pragma unroll
            for (int off = 1; off < 16; off <<= 1) {
                q0 += __shfl_xor(q0, off);
                q1 += __shfl_xor(q1, off);
                q2 += __shfl_xor(q2, off);
                q3 += __shfl_xor(q3, off);
            }
            float a0 = e0 / q0, a1 = e1 / q1, a2 = e2 / q2, a3 = e3 / q3;
            rs_acc += a0 + a1 + a2 + a3;
            int tl = wid * 16 + g * 4;  // t_local base (4 consecutive t)
            ushort2 p0, p1;
            p0.x = bfbits(a0); p0.y = bfbits(a1);
            p1.x = bfbits(a2); p1.y = bfbits(a3);
            int sw = (s15 & 3) << 4;
            *(ushort2*)((char*)as_ + s15 * 64 + ((tl * 2) ^ sw))       = p0;
            *(ushort2*)((char*)as_ + s15 * 64 + (((tl + 2) * 2) ^ sw)) = p1;
            if (write_avis) {
                f32x4 w = {a0, a1, a2, a3};
                *(f32x4*)(avis + (size_t)(b * 16 + s15) * T_ + tb + tl) = w;
            }
        }
        __syncthreads();
        // updates: all 4 waves, 12 d-tiles each
        {
            int pa = s15 * 64 + ((g * 16) ^ ((s15 & 3) << 4));
            s16x8 afr = *(const s16x8*)((const char*)as_ + pa);
            #pragma unroll
            for (int i = 0; i < 12; ++i) {
                int d = (wid * 12 + i) * 16 + s15;
                int pv = d * 64 + ((g * 16) ^ ((d & 3) << 4));
                s16x8 vf = *(const s16x8*)((const char*)vs + pv);
                uacc[i] = __builtin_amdgcn_mfma_f32_16x16x32_bf16(vf, afr, uacc[i], 0, 0, 0);
            }
        }
    }
    // write partial U^T: layout [b][chunk][d][s]
    float* pUb = pU + (size_t)(b * 16 + chunk) * 768 * 16;
    #pragma unroll
    for (int i = 0; i < 12; ++i) {
        int dbase = (wid * 12 + i) * 16 + g * 4;
        #pragma unroll
        for (int j = 0; j < 4; ++j)
            pUb[(size_t)(dbase + j) * 16 + s15] = uacc[i][j];
    }
    // rowsum partial
    rs_acc += __shfl_xor(rs_acc, 16);
    rs_acc += __shfl_xor(rs_acc, 32);
    if (wid < 2 && lane < 16) rsw[wid][s15] = rs_acc;
    __syncthreads();
    if (tid < 16) prs[(b * 16 + chunk) * 16 + tid] = rsw[0][tid] + rsw[1][tid];
}

// reduce partials: upd[b][s][d] = (sum_c pU + EPS*vsum[b][d]) / (sum_c prs + T*EPS)
__global__ void __launch_bounds__(256) attn_reduce_kernel(
    const float* __restrict__ pU, const float* __restrict__ prs,
    const float* __restrict__ vsum, bf16* __restrict__ upd)
{
    int idx = blockIdx.x * 256 + threadIdx.x;   // 16*16*768
    int d = idx % 768;
    int s = (idx / 768) & 15;
    int b = idx / (768 * 16);
    float su = 0.f;
    #pragma unroll
    for (int c = 0; c < 16; ++c) su += pU[((size_t)(b * 16 + c) * 768 + d) * 16 + s];
    float rs = 0.f;
    #pragma unroll
    for (int c = 0; c < 16; ++c) rs += prs[(b * 16 + c) * 16 + s];
    float val = (su + EPS * vsum[b * 768 + d]) / (rs + T_ * EPS);
    upd[idx] = __float2bfloat16(val);
}

// ---------------------------------------------------------------------------
// GRU gates
__global__ void __launch_bounds__(256) gru_gates_kernel(
    const float* __restrict__ gi, const float* __restrict__ gh,
    float* __restrict__ slots, bf16* __restrict__ slots_bf)
{
    int idx = blockIdx.x * 256 + threadIdx.x;
    int r = idx / 768, c = idx - r * 768;
    const float* gir = gi + (size_t)r * 2304;
    const float* ghr = gh + (size_t)r * 2304;
    float ir = gir[c], iz = gir[768 + c], inn = gir[1536 + c];
    float hr = ghr[c], hz = ghr[768 + c], hn  = ghr[1536 + c];
    float rg = 1.f / (1.f + expf(-(ir + hr)));
    float z  = 1.f / (1.f + expf(-(iz + hz)));
    float n  = tanhf(inn + rg * hn);
    float h  = slots[idx];
    float out = (1.f - z) * n + z * h;
    slots[idx] = out;
    slots_bf[idx] = __float2bfloat16(out);
}

// ---------------------------------------------------------------------------
// Clustering epilogue
__global__ void __launch_bounds__(256) cluster_kernel(
    const float* __restrict__ slots, float* __restrict__ out_slots,
    float* __restrict__ out_mask, float* __restrict__ cm_g)
{
    int b = blockIdx.x;
    __shared__ float s[16][768];
    __shared__ float inv[16];
    __shared__ float adj[16][16], tmp[16][16], cw[16][16];
    __shared__ int reset_s;
    const float* sb = slots + (size_t)b * 16 * 768;
    for (int i = threadIdx.x; i < 16 * 768; i += 256) s[i / 768][i % 768] = sb[i];
    __syncthreads();
    if (threadIdx.x < 16) {
        float q = 0.f;
        for (int d = 0; d < 768; ++d) q += s[threadIdx.x][d] * s[threadIdx.x][d];
        inv[threadIdx.x] = 1.f / fmaxf(sqrtf(q), 1e-12f);
    }
    __syncthreads();
    int n = threadIdx.x >> 4, m = threadIdx.x & 15;
    float dot = 0.f;
    for (int d = 0; d < 768; ++d) dot += s[n][d] * s[m][d];
    dot *= inv[n] * inv[m];
    adj[n][m] = ((1.f - dot) < 0.5f) ? 1.f : 0.f;
    __syncthreads();
    #pragma unroll
    for (int it = 0; it < 4; ++it) {
        float t = 0.f;
        #pragma unroll
        for (int j = 0; j < 16; ++j) t += adj[n][j] * adj[j][m];
        tmp[n][m] = fminf(t, 1.f);
        __syncthreads();
        adj[n][m] = tmp[n][m];
        __syncthreads();
    }
    if (threadIdx.x < 16) {
        int mm = threadIdx.x;
        float run = 0.f;
        for (int nn = 0; nn < 16; ++nn) {
            run += adj[nn][mm];
            tmp[nn][mm] = adj[nn][mm] * ((run <= 1.f) ? 1.f : 0.f);
        }
    }
    __syncthreads();
    if (threadIdx.x == 0) {
        int cnt = 0;
        for (int nn = 0; nn < 16; ++nn) {
            bool any = false;
            for (int j = 0; j < 16; ++j) any = any || (tmp[nn][j] > 0.f);
            cnt += any ? 1 : 0;
        }
        reset_s = (cnt < 3) ? 1 : 0;
    }
    __syncthreads();
    if (reset_s) tmp[n][m] = (n == m) ? 1.f : 0.f;
    __syncthreads();
    if (threadIdx.x < 16) {
        float rs = 0.f;
        for (int j = 0; j < 16; ++j) rs += tmp[threadIdx.x][j];
        rs = fmaxf(rs, 1.f);
        for (int j = 0; j < 16; ++j) cw[threadIdx.x][j] = tmp[threadIdx.x][j] / rs;
        bool any = false;
        for (int j = 0; j < 16; ++j) any = any || (tmp[threadIdx.x][j] > 0.f);
        out_mask[b * 16 + threadIdx.x] = any ? 1.f : 0.f;
    }
    cm_g[b * 256 + threadIdx.x] = tmp[n][m];
    __syncthreads();
    for (int i = threadIdx.x; i < 16 * 768; i += 256) {
        int nn = i / 768, d = i - nn * 768;
        float acc = 0.f;
        #pragma unroll
        for (int j = 0; j < 16; ++j) acc += cw[nn][j] * s[j][d];
        out_slots[(size_t)b * 16 * 768 + i] = acc;
    }
}

__global__ void __launch_bounds__(256) cattn_kernel(
    const float* __restrict__ av, const float* __restrict__ cm_g, float* __restrict__ out_attn)
{
    int b = blockIdx.y;
    int t = blockIdx.x * 256 + threadIdx.x;
    __shared__ float cm[16][16];
    cm[threadIdx.x >> 4][threadIdx.x & 15] = cm_g[b * 256 + threadIdx.x];
    __syncthreads();
    float avv[16];
    #pragma unroll
    for (int j = 0; j < 16; ++j) avv[j] = av[((size_t)b * 16 + j) * T_ + t];
    #pragma unroll
    for (int i = 0; i < 16; ++i) {
        float acc = 0.f;
        #pragma unroll
        for (int j = 0; j < 16; ++j) acc += cm[i][j] * avv[j];
        out_attn[((size_t)b * T_ + t) * 16 + i] = acc;
    }
}

// ---------------------------------------------------------------------------
extern "C" void kernel_launch(void* const* d_in, const int* in_sizes, int n_in,
                              void* d_out, int out_size, void* d_ws, size_t ws_size,
                              hipStream_t stream)
{
    const float* x    = (const float*)d_in[0];
    const float* si   = (const float*)d_in[3];
    const float* Wk   = (const float*)d_in[4];
    const float* Wv   = (const float*)d_in[5];
    const float* Wq   = (const float*)d_in[6];
    const float* gwih = (const float*)d_in[7];
    const float* gwhh = (const float*)d_in[8];
    const float* gbih = (const float*)d_in[9];
    const float* gbhh = (const float*)d_in[10];
    const float* w1   = (const float*)d_in[11];
    const float* b1   = (const float*)d_in[12];
    const float* w2   = (const float*)d_in[13];
    const float* b2   = (const float*)d_in[14];
    const float* ling = (const float*)d_in[15];
    const float* linb = (const float*)d_in[16];
    const float* lsg  = (const float*)d_in[17];
    const float* lsb  = (const float*)d_in[18];
    const float* lfg  = (const float*)d_in[19];
    const float* lfb  = (const float*)d_in[20];

    char* w = (char*)d_ws;
    size_t off = 0;
    auto alloc = [&](size_t bytes) { void* p = w + off; off += (bytes + 255) & ~(size_t)255; return p; };
    bf16* xn_vt  = (bf16*)alloc((size_t)B_ * T_ * D_ * 2);   // xn, later vT
    bf16* k_bf   = (bf16*)alloc((size_t)B_ * T_ * S_ * 2);
    bf16* v_bf   = (bf16*)alloc((size_t)B_ * T_ * S_ * 2);
    float* avis  = (float*)alloc((size_t)B_ * NS * T_ * 4);
    float* pU    = (float*)alloc((size_t)B_ * NCHUNK * S_ * NS * 4);
    float* prs   = (float*)alloc((size_t)B_ * NCHUNK * NS * 4);
    float* vsum  = (float*)alloc((size_t)B_ * S_ * 4);
    float* slots = (float*)alloc((size_t)B_ * NS * S_ * 4);
    bf16* slots_bf = (bf16*)alloc((size_t)B_ * NS * S_ * 2);
    bf16* lnsl   = (bf16*)alloc((size_t)B_ * NS * S_ * 2);
    bf16* q_bf   = (bf16*)alloc((size_t)B_ * NS * S_ * 2);
    bf16* upd_bf = (bf16*)alloc((size_t)B_ * NS * S_ * 2);
    float* gi    = (float*)alloc((size_t)B_ * NS * 3 * S_ * 4);
    float* gh    = (float*)alloc((size_t)B_ * NS * 3 * S_ * 4);
    bf16* h1_bf  = (bf16*)alloc((size_t)B_ * NS * 4 * S_ * 2);
    bf16* wq_bf  = (bf16*)alloc((size_t)S_ * S_ * 2);
    bf16* wk_bf  = (bf16*)alloc((size_t)S_ * D_ * 2);
    bf16* wv_bf  = (bf16*)alloc((size_t)S_ * D_ * 2);
    bf16* gwih_bf = (bf16*)alloc((size_t)3 * S_ * S_ * 2);
    bf16* gwhh_bf = (bf16*)alloc((size_t)3 * S_ * S_ * 2);
    bf16* w1_bf  = (bf16*)alloc((size_t)4 * S_ * S_ * 2);
    bf16* w2_bf  = (bf16*)alloc((size_t)S_ * 4 * S_ * 2);
    float* cm_g  = (float*)alloc((size_t)B_ * 256 * 4);

    float* out_slots = (float*)d_out;
    float* out_attn  = out_slots + (size_t)B_ * NS * S_;
    float* out_mask  = out_attn + (size_t)B_ * T_ * NS;

    auto cvt = [&](const float* src, bf16* dst, int n) {
        f2bf_kernel<<<(n + 255) / 256, 256, 0, stream>>>(src, dst, n);
    };
    cvt(Wq, wq_bf, S_ * S_);
    cvt(Wk, wk_bf, S_ * D_);
    cvt(Wv, wv_bf, S_ * D_);
    cvt(gwih, gwih_bf, 3 * S_ * S_);
    cvt(gwhh, gwhh_bf, 3 * S_ * S_);
    cvt(w1, w1_bf, 4 * S_ * S_);
    cvt(w2, w2_bf, S_ * 4 * S_);

    // LN(x) -> xn (bf16)
    ln768_kernel<<<B_ * T_, 256, 0, stream>>>(x, ling, linb, xn_vt);

    // k, v projections (tiled)
    {
        dim3 g(B_ * T_ / 128, S_ / 128);
        gemm128_kernel<<<g, 256, 0, stream>>>(xn_vt, wk_bf, k_bf, B_ * T_, S_, D_);
        gemm128_kernel<<<g, 256, 0, stream>>>(xn_vt, wv_bf, v_bf, B_ * T_, S_, D_);
    }
    // vT (reuse xn buffer), vsum
    {
        dim3 g(T_ / 32, S_ / 32, B_);
        transpose_kernel<<<g, 256, 0, stream>>>(v_bf, xn_vt);
    }
    bf16* vT = xn_vt;
    vsum_kernel<<<B_ * S_ / 4, 256, 0, stream>>>(vT, vsum);

    init_slots_kernel<<<(B_ * NS * S_) / 256, 256, 0, stream>>>(si, slots, slots_bf);

    for (int it = 0; it < NIT; ++it) {
        ln768_kernel<<<B_ * NS, 256, 0, stream>>>(slots, lsg, lsb, lnsl);
        {
            dim3 g(B_ * NS / 16, S_ / 64);
            gemm_skinny_kernel<<<g, 256, 0, stream>>>(lnsl, wq_bf, nullptr, nullptr, q_bf,
                                                      B_ * NS, S_, S_, 0, 0);
        }
        fused_attn_kernel<<<B_ * NCHUNK, 256, 0, stream>>>(q_bf, k_bf, vT, pU, prs, avis,
                                                           (it == NIT - 1) ? 1 : 0);
        attn_reduce_kernel<<<(B_ * NS * S_) / 256, 256, 0, stream>>>(pU, prs, vsum, upd_bf);
        {
            dim3 g(B_ * NS / 16, 3 * S_ / 64);
            gemm_skinny_kernel<<<g, 256, 0, stream>>>(upd_bf, gwih_bf, gbih, gi, nullptr,
                                                      B_ * NS, 3 * S_, S_, 0, 0);
            gemm_skinny_kernel<<<g, 256, 0, stream>>>(slots_bf, gwhh_bf, gbhh, gh, nullptr,
                                                      B_ * NS, 3 * S_, S_, 0, 0);
        }
        gru_gates_kernel<<<(B_ * NS * S_) / 256, 256, 0, stream>>>(gi, gh, slots, slots_bf);
        ln768_kernel<<<B_ * NS, 256, 0, stream>>>(slots, lfg, lfb, lnsl);
        {
            dim3 g(B_ * NS / 16, 4 * S_ / 64);
            gemm_skinny_kernel<<<g, 256, 0, stream>>>(lnsl, w1_bf, b1, nullptr, h1_bf,
                                                      B_ * NS, 4 * S_, S_, 1, 0);
        }
        {
            dim3 g(B_ * NS / 16, S_ / 64);
            gemm_skinny_kernel<<<g, 256, 0, stream>>>(h1_bf, w2_bf, b2, slots, slots_bf,
                                                      B_ * NS, S_, 4 * S_, 0, 1);
        }
    }

    cluster_kernel<<<B_, 256, 0, stream>>>(slots, out_slots, out_mask, cm_g);
    {
        dim3 g(T_ / 256, B_);
        cattn_kernel<<<g, 256, 0, stream>>>(avis, cm_g, out_attn);
    }
}